// Round 7
// baseline (791.796 us; speedup 1.0000x reference)
//
#include <hip/hip_runtime.h>

#define S_N 20000
#define E_N 10000
#define K_N 128
#define D_N 128
#define NEK 40000
#define NSE 500000
#define B_N 2048

typedef __attribute__((ext_vector_type(8))) short bf16x8;
typedef __attribute__((ext_vector_type(4))) float f32x4;

__device__ __forceinline__ unsigned short f2bf(float f){
  unsigned int u = __float_as_uint(f);
  unsigned int r = u + 0x7FFFu + ((u >> 16) & 1u);   // RNE to bf16
  return (unsigned short)(r >> 16);
}
__device__ __forceinline__ float bf2f(unsigned short h){
  return __uint_as_float(((unsigned int)h) << 16);
}

struct GS { const unsigned short* Ah; const unsigned short* Al;
            const unsigned short* Wh; const unsigned short* Wl;
            float* Z; int rows; };
struct CSet { const int* cnt; int n; int* rp; int* cur; };

// ---- hist (+ wprep piggybacked on trailing 8 blocks) ----
#define HB ((NSE+255)/256)
__global__ __launch_bounds__(256) void k_hist(const int* __restrict__ eks, const int* __restrict__ ekd,
      const int* __restrict__ ses, const int* __restrict__ sed,
      int* c_eke, int* c_ekk, int* c_see, int* c_ses,
      const float* __restrict__ GW, const float* __restrict__ Ga,
      unsigned short* __restrict__ wf, float* __restrict__ wa){
  int bb = blockIdx.x;
  if(bb >= HB){
    int g = bb - HB;                         // gate 0..7
    const float* W  = GW + (size_t)g*16384;
    const float* a1 = Ga + (size_t)g*256;    // src-half of attention vector
    unsigned short* whi = wf + (size_t)g*16384;
    unsigned short* wlo = wf + (size_t)(8+g)*16384;
    int t = threadIdx.x, l = t & 63;
    for(int pi = t>>6; pi < 32; pi += 4){
      int c2 = pi >> 2, kt = pi & 3;
      unsigned short h[8], lo[8];
      #pragma unroll
      for(int j=0;j<8;j++){
        int k = kt*32 + (l>>4)*8 + j;
        int c = c2*16 + (l&15);
        float f = W[(size_t)k*128 + c];
        unsigned short hb = f2bf(f);
        h[j] = hb; lo[j] = f2bf(f - bf2f(hb));
      }
      size_t off = ((size_t)pi*64 + l)*8;
      uint4 hv, lv;
      hv.x = (unsigned)h[0] | ((unsigned)h[1]<<16);  hv.y = (unsigned)h[2] | ((unsigned)h[3]<<16);
      hv.z = (unsigned)h[4] | ((unsigned)h[5]<<16);  hv.w = (unsigned)h[6] | ((unsigned)h[7]<<16);
      lv.x = (unsigned)lo[0] | ((unsigned)lo[1]<<16); lv.y = (unsigned)lo[2] | ((unsigned)lo[3]<<16);
      lv.z = (unsigned)lo[4] | ((unsigned)lo[5]<<16); lv.w = (unsigned)lo[6] | ((unsigned)lo[7]<<16);
      *(uint4*)(whi + off) = hv;
      *(uint4*)(wlo + off) = lv;
    }
    for(int k = t; k < 128; k += 256){       // wa[k] = sum_c W[k][c]*a1[c]
      float s = 0.f;
      const float* wr = W + (size_t)k*128;
      for(int c=0;c<128;c++) s += wr[c]*a1[c];
      wa[(size_t)g*128 + k] = s;
    }
    return;
  }
  int i = bb*256 + threadIdx.x;
  if(i < NEK){ atomicAdd(c_eke + eks[i], 1); atomicAdd(c_ekk + (ekd[i]-E_N), 1); }
  if(i < NSE){ atomicAdd(c_see + ses[i], 1); atomicAdd(c_ses + (sed[i]-E_N), 1); }
}

__global__ __launch_bounds__(1024) void k_scan(CSet c0, CSet c1, CSet c2, CSet c3){
  CSet c = c0;
  if(blockIdx.x==1) c=c1; else if(blockIdx.x==2) c=c2; else if(blockIdx.x==3) c=c3;
  __shared__ int part[1024];
  int t = threadIdx.x;
  int n = c.n;
  int chunk = (n + 1023) >> 10;
  int b0 = t * chunk;
  int s = 0;
  for(int i=0;i<chunk;i++){ int idx=b0+i; if(idx<n) s += c.cnt[idx]; }
  part[t] = s;
  __syncthreads();
  for(int off=1; off<1024; off<<=1){
    int v = (t>=off) ? part[t-off] : 0;
    __syncthreads();
    part[t] += v;
    __syncthreads();
  }
  int run = t ? part[t-1] : 0;
  for(int i=0;i<chunk;i++){
    int idx=b0+i;
    if(idx<n){ int cc = c.cnt[idx]; c.rp[idx]=run; c.cur[idx]=run; run += cc; }
  }
  if(t==0) c.rp[n] = part[1023];
}

__global__ __launch_bounds__(256) void k_fill(const int* __restrict__ eks, const int* __restrict__ ekd,
      const int* __restrict__ ses, const int* __restrict__ sed,
      int* u_eke, int* u_ekk, int* u_see, int* u_ses,
      int* o_eke, int* o_ekk, int* o_see, int* o_ses){
  int i = blockIdx.x*256 + threadIdx.x;
  if(i < NEK){
    int a = eks[i], b = ekd[i];
    int pos = atomicAdd(u_eke + a, 1);        o_eke[pos] = b;
    int pos2 = atomicAdd(u_ekk + (b-E_N), 1); o_ekk[pos2] = a;
  }
  if(i < NSE){
    int a = ses[i], b = sed[i];
    int pos = atomicAdd(u_see + a, 1);        o_see[pos] = b;
    int pos2 = atomicAdd(u_ses + (b-E_N), 1); o_ses[pos2] = a;
  }
}

// ---- per-layer state convert: f32 -> bf16 hi/lo + P = exp(h·wa) per gate ----
__global__ __launch_bounds__(256) void k_cvt(const float* __restrict__ kn, const float* __restrict__ ex,
    const float* __restrict__ st,
    unsigned short* __restrict__ knb, unsigned short* __restrict__ exb, unsigned short* __restrict__ stb,
    const float* __restrict__ wa, int l4,
    float* __restrict__ Pefk, float* __restrict__ Pkfe, float* __restrict__ Pufe, float* __restrict__ Pefu){
  int w = (blockIdx.x*256 + threadIdx.x) >> 6;
  int lane = threadIdx.x & 63;
  const float* src; unsigned short *hi, *lo; int r;
  const float* wv1; const float* wv2 = nullptr; float *P1, *P2 = nullptr;
  if(w < K_N){ r = w; src = kn + (size_t)r*128; hi = knb; lo = knb + (size_t)K_N*128;
               wv1 = wa + (size_t)(l4+1)*128; P1 = Pefk; }
  else if(w < K_N + E_N){ r = w - K_N; src = ex + (size_t)r*128; hi = exb; lo = exb + (size_t)E_N*128;
               wv1 = wa + (size_t)(l4+0)*128; P1 = Pkfe;
               wv2 = wa + (size_t)(l4+2)*128; P2 = Pufe; }
  else { r = w - K_N - E_N; if(r >= S_N) return; src = st + (size_t)r*128; hi = stb; lo = stb + (size_t)S_N*128;
               wv1 = wa + (size_t)(l4+3)*128; P1 = Pefu; }
  float2 x = ((const float2*)src)[lane];
  float2 v1 = ((const float2*)wv1)[lane];
  float d1 = x.x*v1.x + x.y*v1.y;
  float d2 = 0.f;
  if(wv2){ float2 v2 = ((const float2*)wv2)[lane]; d2 = x.x*v2.x + x.y*v2.y; }
  #pragma unroll
  for(int off=1; off<64; off<<=1){ d1 += __shfl_xor(d1,off); d2 += __shfl_xor(d2,off); }
  if(lane==0){ P1[r] = expf(d1); if(P2) P2[r] = expf(d2); }
  unsigned short h0 = f2bf(x.x), h1 = f2bf(x.y);
  unsigned short l0 = f2bf(x.x - bf2f(h0)), l1 = f2bf(x.y - bf2f(h1));
  ((ushort2*)(hi + (size_t)r*128))[lane] = make_ushort2(h0,h1);
  ((ushort2*)(lo + (size_t)r*128))[lane] = make_ushort2(l0,l1);
}

// ---- split-bf16 MFMA GEMM (bf16 hi/lo inputs; round-4 proven) ----
#define GT0 4
#define GT1 317
#define GT2 942
#define GT3 1255
__global__ __launch_bounds__(256) void k_gemm(GS g0, GS g1, GS g2, GS g3){
  int b = blockIdx.x;
  GS g; int lt;
  if(b < GT0){ g = g0; lt = b; }
  else if(b < GT1){ g = g1; lt = b - GT0; }
  else if(b < GT2){ g = g2; lt = b - GT1; }
  else { g = g3; lt = b - GT2; }
  int l = threadIdx.x & 63, wv = threadIdx.x >> 6;
  int r0 = lt*32;
  bf16x8 bh[2][4], bl[2][4];
  #pragma unroll
  for(int cs=0; cs<2; cs++)
    #pragma unroll
    for(int kt=0; kt<4; kt++){
      size_t o = (((size_t)((wv*2+cs)*4 + kt))*64 + l)*8;
      bh[cs][kt] = *(const bf16x8*)(g.Wh + o);
      bl[cs][kt] = *(const bf16x8*)(g.Wl + o);
    }
  f32x4 acc[2][2];
  #pragma unroll
  for(int rs=0;rs<2;rs++)
    #pragma unroll
    for(int cs=0;cs<2;cs++) acc[rs][cs] = (f32x4){0.f,0.f,0.f,0.f};
  #pragma unroll
  for(int kt=0; kt<4; kt++){
    bf16x8 ah[2], al[2];
    #pragma unroll
    for(int rs=0; rs<2; rs++){
      size_t ao = ((size_t)(r0 + rs*16 + (l&15)))*128 + kt*32 + (l>>4)*8;
      ah[rs] = *(const bf16x8*)(g.Ah + ao);
      al[rs] = *(const bf16x8*)(g.Al + ao);
    }
    #pragma unroll
    for(int rs=0; rs<2; rs++)
      #pragma unroll
      for(int cs=0; cs<2; cs++){
        acc[rs][cs] = __builtin_amdgcn_mfma_f32_16x16x32_bf16(ah[rs], bh[cs][kt], acc[rs][cs], 0,0,0);
        acc[rs][cs] = __builtin_amdgcn_mfma_f32_16x16x32_bf16(ah[rs], bl[cs][kt], acc[rs][cs], 0,0,0);
        acc[rs][cs] = __builtin_amdgcn_mfma_f32_16x16x32_bf16(al[rs], bh[cs][kt], acc[rs][cs], 0,0,0);
      }
  }
  // C/D layout: col = lane&15, row = (lane>>4)*4 + j
  #pragma unroll
  for(int rs=0; rs<2; rs++)
    #pragma unroll
    for(int cs=0; cs<2; cs++){
      int cb = (wv<<5) + (cs<<4) + (l&15);
      #pragma unroll
      for(int j=0;j<4;j++){
        int rr = r0 + rs*16 + ((l>>4)<<2) + j;
        if(rr < g.rows) g.Z[(size_t)rr*128 + cb] = acc[rs][cs][j];
      }
    }
}

// ---- per-row segment aggregation: QUARTER-wave streams (16 lanes, 32B/lane),
// 4 streams/wave x unroll-4 = 16 row-gathers in flight. After cross-quarter
// reduce (xor 16,32) every lane holds the full sums for its 32B slice. ----
__device__ __forceinline__ void seg_row_q(const float* __restrict__ z, const float* __restrict__ p,
                                          const int* __restrict__ col, int e0, int e1,
                                          int q, int l16, float4& a0O, float4& a1O, float& denO){
  float4 a0 = {0.f,0.f,0.f,0.f}, a1 = {0.f,0.f,0.f,0.f}; float den = 0.f;
  int e = e0 + q;
  for(; e + 12 < e1; e += 16){
    int cA = col[e], cB = col[e+4], cC = col[e+8], cD = col[e+12];
    float xA = p[cA], xB = p[cB], xC = p[cC], xD = p[cD];
    const float4* rA = (const float4*)(z + (size_t)cA*128) + l16*2;
    const float4* rB = (const float4*)(z + (size_t)cB*128) + l16*2;
    const float4* rC = (const float4*)(z + (size_t)cC*128) + l16*2;
    const float4* rD = (const float4*)(z + (size_t)cD*128) + l16*2;
    float4 zA0 = rA[0], zA1 = rA[1];
    float4 zB0 = rB[0], zB1 = rB[1];
    float4 zC0 = rC[0], zC1 = rC[1];
    float4 zD0 = rD[0], zD1 = rD[1];
    a0.x += xA*zA0.x + xB*zB0.x + xC*zC0.x + xD*zD0.x;
    a0.y += xA*zA0.y + xB*zB0.y + xC*zC0.y + xD*zD0.y;
    a0.z += xA*zA0.z + xB*zB0.z + xC*zC0.z + xD*zD0.z;
    a0.w += xA*zA0.w + xB*zB0.w + xC*zC0.w + xD*zD0.w;
    a1.x += xA*zA1.x + xB*zB1.x + xC*zC1.x + xD*zD1.x;
    a1.y += xA*zA1.y + xB*zB1.y + xC*zC1.y + xD*zD1.y;
    a1.z += xA*zA1.z + xB*zB1.z + xC*zC1.z + xD*zD1.z;
    a1.w += xA*zA1.w + xB*zB1.w + xC*zC1.w + xD*zD1.w;
    den += (xA + xB) + (xC + xD);
  }
  for(; e < e1; e += 4){
    int cA = col[e];
    float xA = p[cA];
    const float4* rA = (const float4*)(z + (size_t)cA*128) + l16*2;
    float4 zA0 = rA[0], zA1 = rA[1];
    a0.x += xA*zA0.x; a0.y += xA*zA0.y; a0.z += xA*zA0.z; a0.w += xA*zA0.w;
    a1.x += xA*zA1.x; a1.y += xA*zA1.y; a1.z += xA*zA1.z; a1.w += xA*zA1.w;
    den += xA;
  }
  a0.x += __shfl_xor(a0.x,16); a0.y += __shfl_xor(a0.y,16);
  a0.z += __shfl_xor(a0.z,16); a0.w += __shfl_xor(a0.w,16);
  a1.x += __shfl_xor(a1.x,16); a1.y += __shfl_xor(a1.y,16);
  a1.z += __shfl_xor(a1.z,16); a1.w += __shfl_xor(a1.w,16);
  den  += __shfl_xor(den,16);
  a0.x += __shfl_xor(a0.x,32); a0.y += __shfl_xor(a0.y,32);
  a0.z += __shfl_xor(a0.z,32); a0.w += __shfl_xor(a0.w,32);
  a1.x += __shfl_xor(a1.x,32); a1.y += __shfl_xor(a1.y,32);
  a1.z += __shfl_xor(a1.z,32); a1.w += __shfl_xor(a1.w,32);
  den  += __shfl_xor(den,32);
  a0O = a0; a1O = a1; denO = den;
}

// ---- fused segment + gate kernel. Flattened grid:
// [0,2500): ex rows — ek(Bx)+se(Cx) aggregated in regs, softmax gate, write ex_f.
// [2500,7500): st rows — ses + base -> st_f.
// [7500,7628): kn rows — 4 waves x 4 quarters = 16 streams, + base -> kn_f.
#define S2A 2500
#define S2B 7500
#define S2C 7628
__global__ __launch_bounds__(256) void k_seg2(
    const float* __restrict__ zB, const float* __restrict__ pB, const int* __restrict__ rpB, const int* __restrict__ colB,
    const float* __restrict__ zC, const float* __restrict__ pC, const int* __restrict__ rpC, const int* __restrict__ colC,
    const float* __restrict__ zS, const float* __restrict__ pS, const int* __restrict__ rpS, const int* __restrict__ colS,
    const float* __restrict__ stBase, float* __restrict__ stOut,
    const float* __restrict__ zK, const float* __restrict__ pK, const int* __restrict__ rpK, const int* __restrict__ colK,
    const float* __restrict__ knBase, float* __restrict__ knOut,
    const float* __restrict__ exBase, float* __restrict__ exOut,
    const float* __restrict__ Fwl, const float* __restrict__ Fbl){
  __shared__ float4 red0[4][16];
  __shared__ float4 red1[4][16];
  __shared__ float redd[4];
  int b = blockIdx.x;
  int lane = threadIdx.x & 63, wid = threadIdx.x >> 6;
  int q = lane >> 4, l16 = lane & 15;
  if(b < S2A){
    int row = b*4 + wid;                     // ex row, < 10000
    float4 B0,B1; float dB;
    seg_row_q(zB, pB, colB, rpB[row], rpB[row+1], q, l16, B0, B1, dB);
    float4 C0,C1; float dC;
    seg_row_q(zC, pC, colC, rpC[row], rpC[row+1], q, l16, C0, C1, dC);
    float invB = dB > 0.f ? 1.f/dB : 0.f;
    float invC = dC > 0.f ? 1.f/dC : 0.f;
    B0.x*=invB; B0.y*=invB; B0.z*=invB; B0.w*=invB;
    B1.x*=invB; B1.y*=invB; B1.z*=invB; B1.w*=invB;
    C0.x*=invC; C0.y*=invC; C0.z*=invC; C0.w*=invC;
    C1.x*=invC; C1.y*=invC; C1.z*=invC; C1.w*=invC;
    const float4* exr = (const float4*)(exBase + (size_t)row*128) + l16*2;
    float4 e0 = exr[0], e1 = exr[1];
    const float4* fA = (const float4*)(Fwl       + l16*8);
    const float4* fB = (const float4*)(Fwl + 128 + l16*8);
    const float4* fC = (const float4*)(Fwl + 256 + l16*8);
    const float4* fD = (const float4*)(Fwl + 384 + l16*8);
    float4 fa0 = fA[0], fa1 = fA[1], fb0 = fB[0], fb1 = fB[1];
    float4 fc0 = fC[0], fc1 = fC[1], fd0 = fD[0], fd1 = fD[1];
    float s1 = e0.x*fa0.x + e0.y*fa0.y + e0.z*fa0.z + e0.w*fa0.w
             + e1.x*fa1.x + e1.y*fa1.y + e1.z*fa1.z + e1.w*fa1.w
             + B0.x*fb0.x + B0.y*fb0.y + B0.z*fb0.z + B0.w*fb0.w
             + B1.x*fb1.x + B1.y*fb1.y + B1.z*fb1.z + B1.w*fb1.w;
    float s2 = e0.x*fc0.x + e0.y*fc0.y + e0.z*fc0.z + e0.w*fc0.w
             + e1.x*fc1.x + e1.y*fc1.y + e1.z*fc1.z + e1.w*fc1.w
             + C0.x*fd0.x + C0.y*fd0.y + C0.z*fd0.z + C0.w*fd0.w
             + C1.x*fd1.x + C1.y*fd1.y + C1.z*fd1.z + C1.w*fd1.w;
    #pragma unroll
    for(int off=1; off<16; off<<=1){ s1 += __shfl_xor(s1,off); s2 += __shfl_xor(s2,off); }
    s1 += Fbl[0]; s2 += Fbl[1];
    float mx = fmaxf(s1,s2);
    float pp = expf(s1-mx), qq = expf(s2-mx);
    float iv = 1.f/(pp+qq);
    pp *= iv; qq *= iv;
    if(q==0){
      float4 o0 = {e0.x + pp*B0.x + qq*C0.x, e0.y + pp*B0.y + qq*C0.y,
                   e0.z + pp*B0.z + qq*C0.z, e0.w + pp*B0.w + qq*C0.w};
      float4 o1 = {e1.x + pp*B1.x + qq*C1.x, e1.y + pp*B1.y + qq*C1.y,
                   e1.z + pp*B1.z + qq*C1.z, e1.w + pp*B1.w + qq*C1.w};
      float4* orow = (float4*)(exOut + (size_t)row*128) + l16*2;
      orow[0] = o0; orow[1] = o1;
    }
  } else if(b < S2B){
    int row = (b-S2A)*4 + wid;               // st row, < 20000
    float4 a0,a1; float den;
    seg_row_q(zS, pS, colS, rpS[row], rpS[row+1], q, l16, a0, a1, den);
    float inv = den > 0.f ? 1.f/den : 0.f;
    if(q==0){
      const float4* br = (const float4*)(stBase + (size_t)row*128) + l16*2;
      float4 b0 = br[0], b1 = br[1];
      float4 r0 = {a0.x*inv + b0.x, a0.y*inv + b0.y, a0.z*inv + b0.z, a0.w*inv + b0.w};
      float4 r1 = {a1.x*inv + b1.x, a1.y*inv + b1.y, a1.z*inv + b1.z, a1.w*inv + b1.w};
      float4* orow = (float4*)(stOut + (size_t)row*128) + l16*2;
      orow[0] = r0; orow[1] = r1;
    }
  } else {
    int row = b - S2B;                       // kn row, < 128; 16 streams
    int e0 = rpK[row], e1 = rpK[row+1];
    float4 a0 = {0.f,0.f,0.f,0.f}, a1 = {0.f,0.f,0.f,0.f}; float den = 0.f;
    int str = wid*4 + q;
    int e = e0 + str;
    for(; e + 48 < e1; e += 64){
      int cA = colK[e], cB = colK[e+16], cC = colK[e+32], cD = colK[e+48];
      float xA = pK[cA], xB = pK[cB], xC = pK[cC], xD = pK[cD];
      const float4* rA = (const float4*)(zK + (size_t)cA*128) + l16*2;
      const float4* rB = (const float4*)(zK + (size_t)cB*128) + l16*2;
      const float4* rC = (const float4*)(zK + (size_t)cC*128) + l16*2;
      const float4* rD = (const float4*)(zK + (size_t)cD*128) + l16*2;
      float4 zA0 = rA[0], zA1 = rA[1];
      float4 zB0 = rB[0], zB1 = rB[1];
      float4 zC0 = rC[0], zC1 = rC[1];
      float4 zD0 = rD[0], zD1 = rD[1];
      a0.x += xA*zA0.x + xB*zB0.x + xC*zC0.x + xD*zD0.x;
      a0.y += xA*zA0.y + xB*zB0.y + xC*zC0.y + xD*zD0.y;
      a0.z += xA*zA0.z + xB*zB0.z + xC*zC0.z + xD*zD0.z;
      a0.w += xA*zA0.w + xB*zB0.w + xC*zC0.w + xD*zD0.w;
      a1.x += xA*zA1.x + xB*zB1.x + xC*zC1.x + xD*zD1.x;
      a1.y += xA*zA1.y + xB*zB1.y + xC*zC1.y + xD*zD1.y;
      a1.z += xA*zA1.z + xB*zB1.z + xC*zC1.z + xD*zD1.z;
      a1.w += xA*zA1.w + xB*zB1.w + xC*zC1.w + xD*zD1.w;
      den += (xA + xB) + (xC + xD);
    }
    for(; e < e1; e += 16){
      int cA = colK[e];
      float xA = pK[cA];
      const float4* rA = (const float4*)(zK + (size_t)cA*128) + l16*2;
      float4 zA0 = rA[0], zA1 = rA[1];
      a0.x += xA*zA0.x; a0.y += xA*zA0.y; a0.z += xA*zA0.z; a0.w += xA*zA0.w;
      a1.x += xA*zA1.x; a1.y += xA*zA1.y; a1.z += xA*zA1.z; a1.w += xA*zA1.w;
      den += xA;
    }
    a0.x += __shfl_xor(a0.x,16); a0.y += __shfl_xor(a0.y,16);
    a0.z += __shfl_xor(a0.z,16); a0.w += __shfl_xor(a0.w,16);
    a1.x += __shfl_xor(a1.x,16); a1.y += __shfl_xor(a1.y,16);
    a1.z += __shfl_xor(a1.z,16); a1.w += __shfl_xor(a1.w,16);
    den  += __shfl_xor(den,16);
    a0.x += __shfl_xor(a0.x,32); a0.y += __shfl_xor(a0.y,32);
    a0.z += __shfl_xor(a0.z,32); a0.w += __shfl_xor(a0.w,32);
    a1.x += __shfl_xor(a1.x,32); a1.y += __shfl_xor(a1.y,32);
    a1.z += __shfl_xor(a1.z,32); a1.w += __shfl_xor(a1.w,32);
    den  += __shfl_xor(den,32);
    if(lane < 16){ red0[wid][l16] = a0; red1[wid][l16] = a1; if(l16==0) redd[wid] = den; }
    __syncthreads();
    if(wid) return;
    a0 = red0[0][l16]; a1 = red1[0][l16]; den = redd[0];
    #pragma unroll
    for(int i=1;i<4;i++){
      float4 r0 = red0[i][l16], r1 = red1[i][l16];
      a0.x+=r0.x; a0.y+=r0.y; a0.z+=r0.z; a0.w+=r0.w;
      a1.x+=r1.x; a1.y+=r1.y; a1.z+=r1.z; a1.w+=r1.w;
      den += redd[i];
    }
    float inv = den > 0.f ? 1.f/den : 0.f;
    if(q==0){
      const float4* br = (const float4*)(knBase + (size_t)row*128) + l16*2;
      float4 b0 = br[0], b1 = br[1];
      float4 r0 = {a0.x*inv + b0.x, a0.y*inv + b0.y, a0.z*inv + b0.z, a0.w*inv + b0.w};
      float4 r1 = {a1.x*inv + b1.x, a1.y*inv + b1.y, a1.z*inv + b1.z, a1.w*inv + b1.w};
      float4* orow = (float4*)(knOut + (size_t)row*128) + l16*2;
      orow[0] = r0; orow[1] = r1;
    }
  }
}

// ---- fused outputs ----
__global__ __launch_bounds__(256) void k_out(const float* __restrict__ st, const float* __restrict__ ex,
    const float* __restrict__ kn, const float* __restrict__ disc,
    const int* __restrict__ sid, const int* __restrict__ eid,
    float* out0, float* out1, float* out2, float* out3){
  int w = (blockIdx.x*256 + threadIdx.x) >> 6;
  int lane = threadIdx.x & 63;
  const int ROWW = 3*B_N*64;
  if(w < ROWW){
    int half = lane>>5, l32 = lane&31;
    int r = w*2 + half;
    int sec = r >> 18;              // B_N*128 = 2^18
    int rr = r & 262143;
    int b = rr >> 7, i = rr & 127;
    const float* emb; int srow; float* ob;
    if(sec==0){ emb=st; srow=sid[b]; ob=out0; }
    else if(sec==1){ emb=ex; srow=eid[b]; ob=out1; }
    else { emb=kn; srow=i; ob=out3; }
    f32x4 v = *((const f32x4*)(emb + (size_t)srow*128) + l32);
    __builtin_nontemporal_store(v, (f32x4*)(ob + (size_t)rr*128) + l32);
  } else {
    int i = (w - ROWW)*64 + lane;
    if(i < B_N) out2[i] = disc[eid[i]];
  }
}

extern "C" void kernel_launch(void* const* d_in, const int* in_sizes, int n_in,
                              void* d_out, int out_size, void* d_ws, size_t ws_size,
                              hipStream_t stream){
  (void)in_sizes; (void)out_size; (void)ws_size;
  const float* stu_emb  = (const float*)d_in[0];
  const float* exer_emb = (const float*)d_in[1];
  const float* kn_emb   = (const float*)d_in[2];
  const float* disc_emb = (const float*)d_in[3];
  const float* GW = (const float*)d_in[4];
  const float* Ga = (const float*)d_in[5];
  const float* Fw = (const float*)d_in[6];
  const float* Fb = (const float*)d_in[7];
  int base = n_in - 6;
  const int* sid    = (const int*)d_in[base];
  const int* eid    = (const int*)d_in[base+1];
  const int* ek_src = (const int*)d_in[base+2];
  const int* ek_dst = (const int*)d_in[base+3];
  const int* se_src = (const int*)d_in[base+4];
  const int* se_dst = (const int*)d_in[base+5];

  char* w = (char*)d_ws;
  size_t off = 0;
  auto alloc = [&](size_t bytes)->char*{ char* p = w + off; off += (bytes + 255) & ~(size_t)255; return p; };
  float* st_f = (float*)alloc((size_t)S_N*D_N*4);
  float* ex_f = (float*)alloc((size_t)E_N*D_N*4);
  float* kn_f = (float*)alloc((size_t)K_N*D_N*4);
  float* zefk = (float*)alloc((size_t)K_N*D_N*4);
  float* zkfe = (float*)alloc((size_t)E_N*D_N*4);
  float* zefu = (float*)alloc((size_t)S_N*D_N*4);
  float* zufe = (float*)alloc((size_t)E_N*D_N*4);
  float* Pefk = (float*)alloc((size_t)K_N*4);
  float* Pkfe = (float*)alloc((size_t)E_N*4);
  float* Pefu = (float*)alloc((size_t)S_N*4);
  float* Pufe = (float*)alloc((size_t)E_N*4);
  unsigned short* knb = (unsigned short*)alloc((size_t)K_N*D_N*2*2 + 4096);
  unsigned short* exb = (unsigned short*)alloc((size_t)E_N*D_N*2*2 + 4096);
  unsigned short* stb = (unsigned short*)alloc((size_t)S_N*D_N*2*2 + 4096);
  unsigned short* wf  = (unsigned short*)alloc((size_t)16*16384*2);
  float* wa   = (float*)alloc((size_t)8*128*4);
  int*   cnt  = (int*)alloc((size_t)(2*E_N+K_N+S_N)*4);
  int*   rp   = (int*)alloc((size_t)(2*(E_N+1)+(K_N+1)+(S_N+1))*4);
  int*   cur  = (int*)alloc((size_t)(2*E_N+K_N+S_N)*4);
  int*   col  = (int*)alloc((size_t)(2*NEK+2*NSE)*4);

  int* cnt_eke = cnt;                 int* cnt_ekk = cnt + E_N;
  int* cnt_see = cnt + E_N + K_N;     int* cnt_ses = cnt + 2*E_N + K_N;
  int* cur_eke = cur;                 int* cur_ekk = cur + E_N;
  int* cur_see = cur + E_N + K_N;     int* cur_ses = cur + 2*E_N + K_N;
  int* rp_eke = rp;                                int* rp_ekk = rp + (E_N+1);
  int* rp_see = rp + (E_N+1) + (K_N+1);            int* rp_ses = rp + 2*(E_N+1) + (K_N+1);
  int* col_eke = col;                 int* col_ekk = col + NEK;
  int* col_see = col + 2*NEK;         int* col_ses = col + 2*NEK + NSE;

  // ---- setup: hist(+wprep) -> scan -> fill ----
  hipMemsetAsync(cnt, 0, (size_t)(2*E_N+K_N+S_N)*4, stream);
  k_hist<<<HB+8,256,0,stream>>>(ek_src, ek_dst, se_src, se_dst,
                                cnt_eke, cnt_ekk, cnt_see, cnt_ses,
                                GW, Ga, wf, wa);
  k_scan<<<4,1024,0,stream>>>(CSet{cnt_eke,E_N,rp_eke,cur_eke}, CSet{cnt_ekk,K_N,rp_ekk,cur_ekk},
                              CSet{cnt_see,E_N,rp_see,cur_see}, CSet{cnt_ses,S_N,rp_ses,cur_ses});
  k_fill<<<HB,256,0,stream>>>(ek_src, ek_dst, se_src, se_dst,
                              cur_eke, cur_ekk, cur_see, cur_ses,
                              col_eke, col_ekk, col_see, col_ses);

  const unsigned short* knb_lo = knb + (size_t)K_N*128;
  const unsigned short* exb_lo = exb + (size_t)E_N*128;
  const unsigned short* stb_lo = stb + (size_t)S_N*128;

  for(int l=0; l<2; l++){
    const float* knp = l ? kn_f : kn_emb;
    const float* exp_ = l ? ex_f : exer_emb;
    const float* stp = l ? st_f : stu_emb;
    int l4 = l*4;
    // state -> bf16 hi/lo + pre-exp'd attention scores (once per element)
    k_cvt<<<(K_N+E_N+S_N)/4,256,0,stream>>>(knp, exp_, stp, knb, exb, stb, wa, l4,
                                            Pefk, Pkfe, Pufe, Pefu);
    // 4 gemms, one dispatch: gates (l4+1: kn), (l4+0: ex), (l4+3: st), (l4+2: ex)
    GS g0{knb, knb_lo, wf + (size_t)(l4+1)*16384, wf + (size_t)(8+l4+1)*16384, zefk, K_N};
    GS g1{exb, exb_lo, wf + (size_t)(l4+0)*16384, wf + (size_t)(8+l4+0)*16384, zkfe, E_N};
    GS g2{stb, stb_lo, wf + (size_t)(l4+3)*16384, wf + (size_t)(8+l4+3)*16384, zefu, S_N};
    GS g3{exb, exb_lo, wf + (size_t)(l4+2)*16384, wf + (size_t)(8+l4+2)*16384, zufe, E_N};
    k_gemm<<<GT3,256,0,stream>>>(g0,g1,g2,g3);
    // fused aggregations + ex gate, one dispatch
    k_seg2<<<S2C,256,0,stream>>>(
      zefk - (size_t)E_N*128, Pefk - E_N, rp_eke, col_eke,     // efk (ek by ex) -> Bx regs
      zefu - (size_t)E_N*128, Pefu - E_N, rp_see, col_see,     // efu (se by ex) -> Cx regs
      zufe, Pufe, rp_ses, col_ses, stp, st_f,                  // ufe -> st_f
      zkfe, Pkfe, rp_ekk, col_ekk, knp, kn_f,                  // kfe -> kn_f
      exp_, ex_f, Fw + (size_t)l*3*2*D_N, Fb + (size_t)l*3);   // gate
  }

  float* out  = (float*)d_out;
  float* out0 = out;                           // stu_ts  (B,D,D)
  float* out1 = out0 + (size_t)B_N*D_N*D_N;    // exer_ts (B,D,D)
  float* out2 = out1 + (size_t)B_N*D_N*D_N;    // disc    (B,1)
  float* out3 = out2 + (size_t)B_N;            // kn_ts   (B,K,D)
  int waves = 3*B_N*64 + 32;
  k_out<<<(waves+3)/4,256,0,stream>>>(st_f, ex_f, kn_f, disc_emb, sid, eid, out0, out1, out2, out3);
}

// Round 9
// 746.049 us; speedup vs baseline: 1.0613x; 1.0613x over previous
//
#include <hip/hip_runtime.h>

#define S_N 20000
#define E_N 10000
#define K_N 128
#define D_N 128
#define NEK 40000
#define NSE 500000
#define B_N 2048

typedef __attribute__((ext_vector_type(8))) short bf16x8;
typedef __attribute__((ext_vector_type(4))) float f32x4;

__device__ __forceinline__ unsigned short f2bf(float f){
  unsigned int u = __float_as_uint(f);
  unsigned int r = u + 0x7FFFu + ((u >> 16) & 1u);   // RNE to bf16
  return (unsigned short)(r >> 16);
}
__device__ __forceinline__ float bf2f(unsigned short h){
  return __uint_as_float(((unsigned int)h) << 16);
}

struct GS { const unsigned short* Ah; const unsigned short* Al;
            const unsigned short* Wh; const unsigned short* Wl;
            unsigned short* Z; int rows; };
struct CSet { const int* cnt; int n; int* rp; int* cur; };

// ---- hist (+ wprep piggybacked on trailing 8 blocks) ----
#define HB ((NSE+255)/256)
__global__ __launch_bounds__(256) void k_hist(const int* __restrict__ eks, const int* __restrict__ ekd,
      const int* __restrict__ ses, const int* __restrict__ sed,
      int* c_eke, int* c_ekk, int* c_see, int* c_ses,
      const float* __restrict__ GW, const float* __restrict__ Ga,
      unsigned short* __restrict__ wf, float* __restrict__ wa){
  int bb = blockIdx.x;
  if(bb >= HB){
    int g = bb - HB;                         // gate 0..7
    const float* W  = GW + (size_t)g*16384;
    const float* a1 = Ga + (size_t)g*256;    // src-half of attention vector
    unsigned short* whi = wf + (size_t)g*16384;
    unsigned short* wlo = wf + (size_t)(8+g)*16384;
    int t = threadIdx.x, l = t & 63;
    for(int pi = t>>6; pi < 32; pi += 4){
      int c2 = pi >> 2, kt = pi & 3;
      unsigned short h[8], lo[8];
      #pragma unroll
      for(int j=0;j<8;j++){
        int k = kt*32 + (l>>4)*8 + j;
        int c = c2*16 + (l&15);
        float f = W[(size_t)k*128 + c];
        unsigned short hb = f2bf(f);
        h[j] = hb; lo[j] = f2bf(f - bf2f(hb));
      }
      size_t off = ((size_t)pi*64 + l)*8;
      uint4 hv, lv;
      hv.x = (unsigned)h[0] | ((unsigned)h[1]<<16);  hv.y = (unsigned)h[2] | ((unsigned)h[3]<<16);
      hv.z = (unsigned)h[4] | ((unsigned)h[5]<<16);  hv.w = (unsigned)h[6] | ((unsigned)h[7]<<16);
      lv.x = (unsigned)lo[0] | ((unsigned)lo[1]<<16); lv.y = (unsigned)lo[2] | ((unsigned)lo[3]<<16);
      lv.z = (unsigned)lo[4] | ((unsigned)lo[5]<<16); lv.w = (unsigned)lo[6] | ((unsigned)lo[7]<<16);
      *(uint4*)(whi + off) = hv;
      *(uint4*)(wlo + off) = lv;
    }
    for(int k = t; k < 128; k += 256){       // wa[k] = sum_c W[k][c]*a1[c]
      float s = 0.f;
      const float* wr = W + (size_t)k*128;
      for(int c=0;c<128;c++) s += wr[c]*a1[c];
      wa[(size_t)g*128 + k] = s;
    }
    return;
  }
  int i = bb*256 + threadIdx.x;
  if(i < NEK){ atomicAdd(c_eke + eks[i], 1); atomicAdd(c_ekk + (ekd[i]-E_N), 1); }
  if(i < NSE){ atomicAdd(c_see + ses[i], 1); atomicAdd(c_ses + (sed[i]-E_N), 1); }
}

__global__ __launch_bounds__(1024) void k_scan(CSet c0, CSet c1, CSet c2, CSet c3){
  CSet c = c0;
  if(blockIdx.x==1) c=c1; else if(blockIdx.x==2) c=c2; else if(blockIdx.x==3) c=c3;
  __shared__ int part[1024];
  int t = threadIdx.x;
  int n = c.n;
  int chunk = (n + 1023) >> 10;
  int b0 = t * chunk;
  int s = 0;
  for(int i=0;i<chunk;i++){ int idx=b0+i; if(idx<n) s += c.cnt[idx]; }
  part[t] = s;
  __syncthreads();
  for(int off=1; off<1024; off<<=1){
    int v = (t>=off) ? part[t-off] : 0;
    __syncthreads();
    part[t] += v;
    __syncthreads();
  }
  int run = t ? part[t-1] : 0;
  for(int i=0;i<chunk;i++){
    int idx=b0+i;
    if(idx<n){ int cc = c.cnt[idx]; c.rp[idx]=run; c.cur[idx]=run; run += cc; }
  }
  if(t==0) c.rp[n] = part[1023];
}

__global__ __launch_bounds__(256) void k_fill(const int* __restrict__ eks, const int* __restrict__ ekd,
      const int* __restrict__ ses, const int* __restrict__ sed,
      int* u_eke, int* u_ekk, int* u_see, int* u_ses,
      int* o_eke, int* o_ekk, int* o_see, int* o_ses){
  int i = blockIdx.x*256 + threadIdx.x;
  if(i < NEK){
    int a = eks[i], b = ekd[i];
    int pos = atomicAdd(u_eke + a, 1);        o_eke[pos] = b;
    int pos2 = atomicAdd(u_ekk + (b-E_N), 1); o_ekk[pos2] = a;
  }
  if(i < NSE){
    int a = ses[i], b = sed[i];
    int pos = atomicAdd(u_see + a, 1);        o_see[pos] = b;
    int pos2 = atomicAdd(u_ses + (b-E_N), 1); o_ses[pos2] = a;
  }
}

// ---- per-layer state convert: f32 -> bf16 hi/lo + P = exp(h·wa) per gate ----
__global__ __launch_bounds__(256) void k_cvt(const float* __restrict__ kn, const float* __restrict__ ex,
    const float* __restrict__ st,
    unsigned short* __restrict__ knb, unsigned short* __restrict__ exb, unsigned short* __restrict__ stb,
    const float* __restrict__ wa, int l4,
    float* __restrict__ Pefk, float* __restrict__ Pkfe, float* __restrict__ Pufe, float* __restrict__ Pefu){
  int w = (blockIdx.x*256 + threadIdx.x) >> 6;
  int lane = threadIdx.x & 63;
  const float* src; unsigned short *hi, *lo; int r;
  const float* wv1; const float* wv2 = nullptr; float *P1, *P2 = nullptr;
  if(w < K_N){ r = w; src = kn + (size_t)r*128; hi = knb; lo = knb + (size_t)K_N*128;
               wv1 = wa + (size_t)(l4+1)*128; P1 = Pefk; }
  else if(w < K_N + E_N){ r = w - K_N; src = ex + (size_t)r*128; hi = exb; lo = exb + (size_t)E_N*128;
               wv1 = wa + (size_t)(l4+0)*128; P1 = Pkfe;
               wv2 = wa + (size_t)(l4+2)*128; P2 = Pufe; }
  else { r = w - K_N - E_N; if(r >= S_N) return; src = st + (size_t)r*128; hi = stb; lo = stb + (size_t)S_N*128;
               wv1 = wa + (size_t)(l4+3)*128; P1 = Pefu; }
  float2 x = ((const float2*)src)[lane];
  float2 v1 = ((const float2*)wv1)[lane];
  float d1 = x.x*v1.x + x.y*v1.y;
  float d2 = 0.f;
  if(wv2){ float2 v2 = ((const float2*)wv2)[lane]; d2 = x.x*v2.x + x.y*v2.y; }
  #pragma unroll
  for(int off=1; off<64; off<<=1){ d1 += __shfl_xor(d1,off); d2 += __shfl_xor(d2,off); }
  if(lane==0){ P1[r] = expf(d1); if(P2) P2[r] = expf(d2); }
  unsigned short h0 = f2bf(x.x), h1 = f2bf(x.y);
  unsigned short l0 = f2bf(x.x - bf2f(h0)), l1 = f2bf(x.y - bf2f(h1));
  ((ushort2*)(hi + (size_t)r*128))[lane] = make_ushort2(h0,h1);
  ((ushort2*)(lo + (size_t)r*128))[lane] = make_ushort2(l0,l1);
}

// ---- split-bf16 MFMA GEMM; Z output packed bf16 (RNE) via lane-pair pack ----
#define GT0 4
#define GT1 317
#define GT2 942
#define GT3 1255
__global__ __launch_bounds__(256) void k_gemm(GS g0, GS g1, GS g2, GS g3){
  int b = blockIdx.x;
  GS g; int lt;
  if(b < GT0){ g = g0; lt = b; }
  else if(b < GT1){ g = g1; lt = b - GT0; }
  else if(b < GT2){ g = g2; lt = b - GT1; }
  else { g = g3; lt = b - GT2; }
  int l = threadIdx.x & 63, wv = threadIdx.x >> 6;
  int r0 = lt*32;
  bf16x8 bh[2][4], bl[2][4];
  #pragma unroll
  for(int cs=0; cs<2; cs++)
    #pragma unroll
    for(int kt=0; kt<4; kt++){
      size_t o = (((size_t)((wv*2+cs)*4 + kt))*64 + l)*8;
      bh[cs][kt] = *(const bf16x8*)(g.Wh + o);
      bl[cs][kt] = *(const bf16x8*)(g.Wl + o);
    }
  f32x4 acc[2][2];
  #pragma unroll
  for(int rs=0;rs<2;rs++)
    #pragma unroll
    for(int cs=0;cs<2;cs++) acc[rs][cs] = (f32x4){0.f,0.f,0.f,0.f};
  #pragma unroll
  for(int kt=0; kt<4; kt++){
    bf16x8 ah[2], al[2];
    #pragma unroll
    for(int rs=0; rs<2; rs++){
      size_t ao = ((size_t)(r0 + rs*16 + (l&15)))*128 + kt*32 + (l>>4)*8;
      ah[rs] = *(const bf16x8*)(g.Ah + ao);
      al[rs] = *(const bf16x8*)(g.Al + ao);
    }
    #pragma unroll
    for(int rs=0; rs<2; rs++)
      #pragma unroll
      for(int cs=0; cs<2; cs++){
        acc[rs][cs] = __builtin_amdgcn_mfma_f32_16x16x32_bf16(ah[rs], bh[cs][kt], acc[rs][cs], 0,0,0);
        acc[rs][cs] = __builtin_amdgcn_mfma_f32_16x16x32_bf16(ah[rs], bl[cs][kt], acc[rs][cs], 0,0,0);
        acc[rs][cs] = __builtin_amdgcn_mfma_f32_16x16x32_bf16(al[rs], bh[cs][kt], acc[rs][cs], 0,0,0);
      }
  }
  // C/D layout: col = lane&15, row = (lane>>4)*4 + j.
  // Lanes l and l^1 hold adjacent cols of the SAME row -> pack 2 bf16 per dword.
  #pragma unroll
  for(int rs=0; rs<2; rs++)
    #pragma unroll
    for(int cs=0; cs<2; cs++){
      int cb = (wv<<5) + (cs<<4) + (l&15);
      #pragma unroll
      for(int j=0;j<4;j++){
        float v = acc[rs][cs][j];
        float vp = __shfl_xor(v, 1);
        int rr = r0 + rs*16 + ((l>>4)<<2) + j;
        if(!(l&1) && rr < g.rows){
          unsigned int pw = (unsigned)f2bf(v) | ((unsigned)f2bf(vp)<<16);
          *(unsigned int*)(g.Z + (size_t)rr*128 + cb) = pw;
        }
      }
    }
}

// ---- segment aggregation over bf16 z: quarter-wave (16 lanes x 16B = full row),
// unroll-4 -> 16 row-gathers in flight/wave; f32 accumulate; cross-quarter reduce. ----
#define BFACC(zz, xx) \
  a[0] += xx*__uint_as_float(zz.x<<16); a[1] += xx*__uint_as_float(zz.x&0xffff0000u); \
  a[2] += xx*__uint_as_float(zz.y<<16); a[3] += xx*__uint_as_float(zz.y&0xffff0000u); \
  a[4] += xx*__uint_as_float(zz.z<<16); a[5] += xx*__uint_as_float(zz.z&0xffff0000u); \
  a[6] += xx*__uint_as_float(zz.w<<16); a[7] += xx*__uint_as_float(zz.w&0xffff0000u);

__device__ __forceinline__ void seg_row_q(const unsigned short* __restrict__ z, const float* __restrict__ p,
                                          const int* __restrict__ col, int e0, int e1,
                                          int q, int l16, float* a, float& denO){
  #pragma unroll
  for(int j=0;j<8;j++) a[j] = 0.f;
  float den = 0.f;
  const unsigned short* zl = z + l16*8;
  int e = e0 + q;
  for(; e + 12 < e1; e += 16){
    int cA = col[e], cB = col[e+4], cC = col[e+8], cD = col[e+12];
    float xA = p[cA], xB = p[cB], xC = p[cC], xD = p[cD];
    uint4 zA = *(const uint4*)(zl + (size_t)cA*128);
    uint4 zB = *(const uint4*)(zl + (size_t)cB*128);
    uint4 zC = *(const uint4*)(zl + (size_t)cC*128);
    uint4 zD = *(const uint4*)(zl + (size_t)cD*128);
    BFACC(zA,xA) BFACC(zB,xB) BFACC(zC,xC) BFACC(zD,xD)
    den += (xA + xB) + (xC + xD);
  }
  for(; e < e1; e += 4){
    int cA = col[e];
    float xA = p[cA];
    uint4 zA = *(const uint4*)(zl + (size_t)cA*128);
    BFACC(zA,xA)
    den += xA;
  }
  #pragma unroll
  for(int j=0;j<8;j++){ a[j] += __shfl_xor(a[j],16); a[j] += __shfl_xor(a[j],32); }
  den += __shfl_xor(den,16); den += __shfl_xor(den,32);
  denO = den;
}

// ---- fused segment + gate kernel. Flattened grid:
// [0,2500): ex rows — ek(Bx)+se(Cx) in regs, softmax gate, write ex_f.
// [2500,7500): st rows — ses + base -> st_f.
// [7500,7628): kn rows — 4 waves x 4 quarters = 16 streams, + base -> kn_f.
#define S2A 2500
#define S2B 7500
#define S2C 7628
__global__ __launch_bounds__(256) void k_seg2(
    const unsigned short* __restrict__ zB, const float* __restrict__ pB, const int* __restrict__ rpB, const int* __restrict__ colB,
    const unsigned short* __restrict__ zC, const float* __restrict__ pC, const int* __restrict__ rpC, const int* __restrict__ colC,
    const unsigned short* __restrict__ zS, const float* __restrict__ pS, const int* __restrict__ rpS, const int* __restrict__ colS,
    const float* __restrict__ stBase, float* __restrict__ stOut,
    const unsigned short* __restrict__ zK, const float* __restrict__ pK, const int* __restrict__ rpK, const int* __restrict__ colK,
    const float* __restrict__ knBase, float* __restrict__ knOut,
    const float* __restrict__ exBase, float* __restrict__ exOut,
    const float* __restrict__ Fwl, const float* __restrict__ Fbl){
  __shared__ float4 red0[4][16];
  __shared__ float4 red1[4][16];
  __shared__ float redd[4];
  int b = blockIdx.x;
  int lane = threadIdx.x & 63, wid = threadIdx.x >> 6;
  int q = lane >> 4, l16 = lane & 15;
  if(b < S2A){
    int row = b*4 + wid;                     // ex row, < 10000
    float B[8], C[8]; float dB, dC;
    seg_row_q(zB, pB, colB, rpB[row], rpB[row+1], q, l16, B, dB);
    seg_row_q(zC, pC, colC, rpC[row], rpC[row+1], q, l16, C, dC);
    float invB = dB > 0.f ? 1.f/dB : 0.f;
    float invC = dC > 0.f ? 1.f/dC : 0.f;
    #pragma unroll
    for(int j=0;j<8;j++){ B[j]*=invB; C[j]*=invC; }
    const float4* exr = (const float4*)(exBase + (size_t)row*128) + l16*2;
    float4 ea = exr[0], eb = exr[1];
    float ex8[8] = {ea.x,ea.y,ea.z,ea.w, eb.x,eb.y,eb.z,eb.w};
    float s1 = 0.f, s2 = 0.f;
    #pragma unroll
    for(int j=0;j<8;j++){
      s1 += ex8[j]*Fwl[l16*8+j]       + B[j]*Fwl[128+l16*8+j];
      s2 += ex8[j]*Fwl[256+l16*8+j]   + C[j]*Fwl[384+l16*8+j];
    }
    #pragma unroll
    for(int off=1; off<16; off<<=1){ s1 += __shfl_xor(s1,off); s2 += __shfl_xor(s2,off); }
    s1 += Fbl[0]; s2 += Fbl[1];
    float mx = fmaxf(s1,s2);
    float pp = expf(s1-mx), qq = expf(s2-mx);
    float iv = 1.f/(pp+qq);
    pp *= iv; qq *= iv;
    if(q==0){
      float o8[8];
      #pragma unroll
      for(int j=0;j<8;j++) o8[j] = ex8[j] + pp*B[j] + qq*C[j];
      float4* orow = (float4*)(exOut + (size_t)row*128) + l16*2;
      orow[0] = (float4){o8[0],o8[1],o8[2],o8[3]};
      orow[1] = (float4){o8[4],o8[5],o8[6],o8[7]};
    }
  } else if(b < S2B){
    int row = (b-S2A)*4 + wid;               // st row, < 20000
    float a[8]; float den;
    seg_row_q(zS, pS, colS, rpS[row], rpS[row+1], q, l16, a, den);
    float inv = den > 0.f ? 1.f/den : 0.f;
    if(q==0){
      const float4* br = (const float4*)(stBase + (size_t)row*128) + l16*2;
      float4 b0 = br[0], b1 = br[1];
      float4* orow = (float4*)(stOut + (size_t)row*128) + l16*2;
      orow[0] = (float4){a[0]*inv + b0.x, a[1]*inv + b0.y, a[2]*inv + b0.z, a[3]*inv + b0.w};
      orow[1] = (float4){a[4]*inv + b1.x, a[5]*inv + b1.y, a[6]*inv + b1.z, a[7]*inv + b1.w};
    }
  } else {
    int row = b - S2B;                       // kn row, < 128; 16 streams
    int e0 = rpK[row], e1 = rpK[row+1];
    float a[8];
    #pragma unroll
    for(int j=0;j<8;j++) a[j]=0.f;
    float den = 0.f;
    const unsigned short* zl = zK + l16*8;
    int str = wid*4 + q;
    int e = e0 + str;
    for(; e + 48 < e1; e += 64){
      int cA = colK[e], cB = colK[e+16], cC = colK[e+32], cD = colK[e+48];
      float xA = pK[cA], xB = pK[cB], xC = pK[cC], xD = pK[cD];
      uint4 zA = *(const uint4*)(zl + (size_t)cA*128);
      uint4 zB = *(const uint4*)(zl + (size_t)cB*128);
      uint4 zC = *(const uint4*)(zl + (size_t)cC*128);
      uint4 zD = *(const uint4*)(zl + (size_t)cD*128);
      BFACC(zA,xA) BFACC(zB,xB) BFACC(zC,xC) BFACC(zD,xD)
      den += (xA + xB) + (xC + xD);
    }
    for(; e < e1; e += 16){
      int cA = colK[e];
      float xA = pK[cA];
      uint4 zA = *(const uint4*)(zl + (size_t)cA*128);
      BFACC(zA,xA)
      den += xA;
    }
    #pragma unroll
    for(int j=0;j<8;j++){ a[j] += __shfl_xor(a[j],16); a[j] += __shfl_xor(a[j],32); }
    den += __shfl_xor(den,16); den += __shfl_xor(den,32);
    if(lane < 16){
      red0[wid][l16] = (float4){a[0],a[1],a[2],a[3]};
      red1[wid][l16] = (float4){a[4],a[5],a[6],a[7]};
      if(l16==0) redd[wid] = den;
    }
    __syncthreads();
    if(wid) return;
    float4 a0 = red0[0][l16], a1 = red1[0][l16]; den = redd[0];
    #pragma unroll
    for(int i=1;i<4;i++){
      float4 r0 = red0[i][l16], r1 = red1[i][l16];
      a0.x+=r0.x; a0.y+=r0.y; a0.z+=r0.z; a0.w+=r0.w;
      a1.x+=r1.x; a1.y+=r1.y; a1.z+=r1.z; a1.w+=r1.w;
      den += redd[i];
    }
    float inv = den > 0.f ? 1.f/den : 0.f;
    if(q==0){
      const float4* br = (const float4*)(knBase + (size_t)row*128) + l16*2;
      float4 b0 = br[0], b1 = br[1];
      float4* orow = (float4*)(knOut + (size_t)row*128) + l16*2;
      orow[0] = (float4){a0.x*inv + b0.x, a0.y*inv + b0.y, a0.z*inv + b0.z, a0.w*inv + b0.w};
      orow[1] = (float4){a1.x*inv + b1.x, a1.y*inv + b1.y, a1.z*inv + b1.z, a1.w*inv + b1.w};
    }
  }
}

// ---- fused outputs ----
__global__ __launch_bounds__(256) void k_out(const float* __restrict__ st, const float* __restrict__ ex,
    const float* __restrict__ kn, const float* __restrict__ disc,
    const int* __restrict__ sid, const int* __restrict__ eid,
    float* out0, float* out1, float* out2, float* out3){
  int w = (blockIdx.x*256 + threadIdx.x) >> 6;
  int lane = threadIdx.x & 63;
  const int ROWW = 3*B_N*64;
  if(w < ROWW){
    int half = lane>>5, l32 = lane&31;
    int r = w*2 + half;
    int sec = r >> 18;              // B_N*128 = 2^18
    int rr = r & 262143;
    int b = rr >> 7, i = rr & 127;
    const float* emb; int srow; float* ob;
    if(sec==0){ emb=st; srow=sid[b]; ob=out0; }
    else if(sec==1){ emb=ex; srow=eid[b]; ob=out1; }
    else { emb=kn; srow=i; ob=out3; }
    f32x4 v = *((const f32x4*)(emb + (size_t)srow*128) + l32);
    __builtin_nontemporal_store(v, (f32x4*)(ob + (size_t)rr*128) + l32);
  } else {
    int i = (w - ROWW)*64 + lane;
    if(i < B_N) out2[i] = disc[eid[i]];
  }
}

extern "C" void kernel_launch(void* const* d_in, const int* in_sizes, int n_in,
                              void* d_out, int out_size, void* d_ws, size_t ws_size,
                              hipStream_t stream){
  (void)in_sizes; (void)out_size; (void)ws_size;
  const float* stu_emb  = (const float*)d_in[0];
  const float* exer_emb = (const float*)d_in[1];
  const float* kn_emb   = (const float*)d_in[2];
  const float* disc_emb = (const float*)d_in[3];
  const float* GW = (const float*)d_in[4];
  const float* Ga = (const float*)d_in[5];
  const float* Fw = (const float*)d_in[6];
  const float* Fb = (const float*)d_in[7];
  int base = n_in - 6;
  const int* sid    = (const int*)d_in[base];
  const int* eid    = (const int*)d_in[base+1];
  const int* ek_src = (const int*)d_in[base+2];
  const int* ek_dst = (const int*)d_in[base+3];
  const int* se_src = (const int*)d_in[base+4];
  const int* se_dst = (const int*)d_in[base+5];

  char* w = (char*)d_ws;
  size_t off = 0;
  auto alloc = [&](size_t bytes)->char*{ char* p = w + off; off += (bytes + 255) & ~(size_t)255; return p; };
  float* st_f = (float*)alloc((size_t)S_N*D_N*4);
  float* ex_f = (float*)alloc((size_t)E_N*D_N*4);
  float* kn_f = (float*)alloc((size_t)K_N*D_N*4);
  unsigned short* zefk = (unsigned short*)alloc((size_t)K_N*D_N*2);
  unsigned short* zkfe = (unsigned short*)alloc((size_t)E_N*D_N*2);
  unsigned short* zefu = (unsigned short*)alloc((size_t)S_N*D_N*2);
  unsigned short* zufe = (unsigned short*)alloc((size_t)E_N*D_N*2);
  float* Pefk = (float*)alloc((size_t)K_N*4);
  float* Pkfe = (float*)alloc((size_t)E_N*4);
  float* Pefu = (float*)alloc((size_t)S_N*4);
  float* Pufe = (float*)alloc((size_t)E_N*4);
  unsigned short* knb = (unsigned short*)alloc((size_t)K_N*D_N*2*2 + 4096);
  unsigned short* exb = (unsigned short*)alloc((size_t)E_N*D_N*2*2 + 4096);
  unsigned short* stb = (unsigned short*)alloc((size_t)S_N*D_N*2*2 + 4096);
  unsigned short* wf  = (unsigned short*)alloc((size_t)16*16384*2);
  float* wa   = (float*)alloc((size_t)8*128*4);
  int*   cnt  = (int*)alloc((size_t)(2*E_N+K_N+S_N)*4);
  int*   rp   = (int*)alloc((size_t)(2*(E_N+1)+(K_N+1)+(S_N+1))*4);
  int*   cur  = (int*)alloc((size_t)(2*E_N+K_N+S_N)*4);
  int*   col  = (int*)alloc((size_t)(2*NEK+2*NSE)*4);

  int* cnt_eke = cnt;                 int* cnt_ekk = cnt + E_N;
  int* cnt_see = cnt + E_N + K_N;     int* cnt_ses = cnt + 2*E_N + K_N;
  int* cur_eke = cur;                 int* cur_ekk = cur + E_N;
  int* cur_see = cur + E_N + K_N;     int* cur_ses = cur + 2*E_N + K_N;
  int* rp_eke = rp;                                int* rp_ekk = rp + (E_N+1);
  int* rp_see = rp + (E_N+1) + (K_N+1);            int* rp_ses = rp + 2*(E_N+1) + (K_N+1);
  int* col_eke = col;                 int* col_ekk = col + NEK;
  int* col_see = col + 2*NEK;         int* col_ses = col + 2*NEK + NSE;

  // ---- setup: hist(+wprep) -> scan -> fill ----
  hipMemsetAsync(cnt, 0, (size_t)(2*E_N+K_N+S_N)*4, stream);
  k_hist<<<HB+8,256,0,stream>>>(ek_src, ek_dst, se_src, se_dst,
                                cnt_eke, cnt_ekk, cnt_see, cnt_ses,
                                GW, Ga, wf, wa);
  k_scan<<<4,1024,0,stream>>>(CSet{cnt_eke,E_N,rp_eke,cur_eke}, CSet{cnt_ekk,K_N,rp_ekk,cur_ekk},
                              CSet{cnt_see,E_N,rp_see,cur_see}, CSet{cnt_ses,S_N,rp_ses,cur_ses});
  k_fill<<<HB,256,0,stream>>>(ek_src, ek_dst, se_src, se_dst,
                              cur_eke, cur_ekk, cur_see, cur_ses,
                              col_eke, col_ekk, col_see, col_ses);

  const unsigned short* knb_lo = knb + (size_t)K_N*128;
  const unsigned short* exb_lo = exb + (size_t)E_N*128;
  const unsigned short* stb_lo = stb + (size_t)S_N*128;

  for(int l=0; l<2; l++){
    const float* knp = l ? kn_f : kn_emb;
    const float* exp_ = l ? ex_f : exer_emb;
    const float* stp = l ? st_f : stu_emb;
    int l4 = l*4;
    // state -> bf16 hi/lo + pre-exp'd attention scores (once per element)
    k_cvt<<<(K_N+E_N+S_N)/4,256,0,stream>>>(knp, exp_, stp, knb, exb, stb, wa, l4,
                                            Pefk, Pkfe, Pufe, Pefu);
    // 4 gemms, one dispatch: gates (l4+1: kn), (l4+0: ex), (l4+3: st), (l4+2: ex)
    GS g0{knb, knb_lo, wf + (size_t)(l4+1)*16384, wf + (size_t)(8+l4+1)*16384, zefk, K_N};
    GS g1{exb, exb_lo, wf + (size_t)(l4+0)*16384, wf + (size_t)(8+l4+0)*16384, zkfe, E_N};
    GS g2{stb, stb_lo, wf + (size_t)(l4+3)*16384, wf + (size_t)(8+l4+3)*16384, zefu, S_N};
    GS g3{exb, exb_lo, wf + (size_t)(l4+2)*16384, wf + (size_t)(8+l4+2)*16384, zufe, E_N};
    k_gemm<<<GT3,256,0,stream>>>(g0,g1,g2,g3);
    // fused aggregations + ex gate, one dispatch
    k_seg2<<<S2C,256,0,stream>>>(
      zefk - (size_t)E_N*128, Pefk - E_N, rp_eke, col_eke,     // efk (ek by ex)
      zefu - (size_t)E_N*128, Pefu - E_N, rp_see, col_see,     // efu (se by ex)
      zufe, Pufe, rp_ses, col_ses, stp, st_f,                  // ufe -> st_f
      zkfe, Pkfe, rp_ekk, col_ekk, knp, kn_f,                  // kfe -> kn_f
      exp_, ex_f, Fw + (size_t)l*3*2*D_N, Fb + (size_t)l*3);   // gate
  }

  float* out  = (float*)d_out;
  float* out0 = out;                           // stu_ts  (B,D,D)
  float* out1 = out0 + (size_t)B_N*D_N*D_N;    // exer_ts (B,D,D)
  float* out2 = out1 + (size_t)B_N*D_N*D_N;    // disc    (B,1)
  float* out3 = out2 + (size_t)B_N;            // kn_ts   (B,K,D)
  int waves = 3*B_N*64 + 32;
  k_out<<<(waves+3)/4,256,0,stream>>>(st_f, ex_f, kn_f, disc_emb, sid, eid, out0, out1, out2, out3);
}

// Round 10
// 730.933 us; speedup vs baseline: 1.0833x; 1.0207x over previous
//
#include <hip/hip_runtime.h>

#define S_N 20000
#define E_N 10000
#define K_N 128
#define D_N 128
#define NEK 40000
#define NSE 500000
#define B_N 2048

typedef __attribute__((ext_vector_type(8))) short bf16x8;
typedef __attribute__((ext_vector_type(4))) float f32x4;

__device__ __forceinline__ unsigned short f2bf(float f){
  unsigned int u = __float_as_uint(f);
  unsigned int r = u + 0x7FFFu + ((u >> 16) & 1u);   // RNE to bf16
  return (unsigned short)(r >> 16);
}
__device__ __forceinline__ float bf2f(unsigned short h){
  return __uint_as_float(((unsigned int)h) << 16);
}

struct GS { const unsigned short* Ah; const unsigned short* Al;
            const unsigned short* Wh; const unsigned short* Wl;
            unsigned short* Z; int rows; };
struct CSet { const int* cnt; int n; int* rp; int* cur; };

// ---- hist (+ wprep piggybacked on trailing 8 blocks) ----
#define HB ((NSE+255)/256)
__global__ __launch_bounds__(256) void k_hist(const int* __restrict__ eks, const int* __restrict__ ekd,
      const int* __restrict__ ses, const int* __restrict__ sed,
      int* c_eke, int* c_ekk, int* c_see, int* c_ses,
      const float* __restrict__ GW, const float* __restrict__ Ga,
      unsigned short* __restrict__ wf, float* __restrict__ wa){
  int bb = blockIdx.x;
  if(bb >= HB){
    int g = bb - HB;                         // gate 0..7
    const float* W  = GW + (size_t)g*16384;
    const float* a1 = Ga + (size_t)g*256;    // src-half of attention vector
    unsigned short* whi = wf + (size_t)g*16384;
    unsigned short* wlo = wf + (size_t)(8+g)*16384;
    int t = threadIdx.x, l = t & 63;
    for(int pi = t>>6; pi < 32; pi += 4){
      int c2 = pi >> 2, kt = pi & 3;
      unsigned short h[8], lo[8];
      #pragma unroll
      for(int j=0;j<8;j++){
        int k = kt*32 + (l>>4)*8 + j;
        int c = c2*16 + (l&15);
        float f = W[(size_t)k*128 + c];
        unsigned short hb = f2bf(f);
        h[j] = hb; lo[j] = f2bf(f - bf2f(hb));
      }
      size_t off = ((size_t)pi*64 + l)*8;
      uint4 hv, lv;
      hv.x = (unsigned)h[0] | ((unsigned)h[1]<<16);  hv.y = (unsigned)h[2] | ((unsigned)h[3]<<16);
      hv.z = (unsigned)h[4] | ((unsigned)h[5]<<16);  hv.w = (unsigned)h[6] | ((unsigned)h[7]<<16);
      lv.x = (unsigned)lo[0] | ((unsigned)lo[1]<<16); lv.y = (unsigned)lo[2] | ((unsigned)lo[3]<<16);
      lv.z = (unsigned)lo[4] | ((unsigned)lo[5]<<16); lv.w = (unsigned)lo[6] | ((unsigned)lo[7]<<16);
      *(uint4*)(whi + off) = hv;
      *(uint4*)(wlo + off) = lv;
    }
    for(int k = t; k < 128; k += 256){       // wa[k] = sum_c W[k][c]*a1[c]
      float s = 0.f;
      const float* wr = W + (size_t)k*128;
      for(int c=0;c<128;c++) s += wr[c]*a1[c];
      wa[(size_t)g*128 + k] = s;
    }
    return;
  }
  int i = bb*256 + threadIdx.x;
  if(i < NEK){ atomicAdd(c_eke + eks[i], 1); atomicAdd(c_ekk + (ekd[i]-E_N), 1); }
  if(i < NSE){ atomicAdd(c_see + ses[i], 1); atomicAdd(c_ses + (sed[i]-E_N), 1); }
}

__global__ __launch_bounds__(1024) void k_scan(CSet c0, CSet c1, CSet c2, CSet c3){
  CSet c = c0;
  if(blockIdx.x==1) c=c1; else if(blockIdx.x==2) c=c2; else if(blockIdx.x==3) c=c3;
  __shared__ int part[1024];
  int t = threadIdx.x;
  int n = c.n;
  int chunk = (n + 1023) >> 10;
  int b0 = t * chunk;
  int s = 0;
  for(int i=0;i<chunk;i++){ int idx=b0+i; if(idx<n) s += c.cnt[idx]; }
  part[t] = s;
  __syncthreads();
  for(int off=1; off<1024; off<<=1){
    int v = (t>=off) ? part[t-off] : 0;
    __syncthreads();
    part[t] += v;
    __syncthreads();
  }
  int run = t ? part[t-1] : 0;
  for(int i=0;i<chunk;i++){
    int idx=b0+i;
    if(idx<n){ int cc = c.cnt[idx]; c.rp[idx]=run; c.cur[idx]=run; run += cc; }
  }
  if(t==0) c.rp[n] = part[1023];
}

__global__ __launch_bounds__(256) void k_fill(const int* __restrict__ eks, const int* __restrict__ ekd,
      const int* __restrict__ ses, const int* __restrict__ sed,
      int* u_eke, int* u_ekk, int* u_see, int* u_ses,
      int* o_eke, int* o_ekk, int* o_see, int* o_ses){
  int i = blockIdx.x*256 + threadIdx.x;
  if(i < NEK){
    int a = eks[i], b = ekd[i];
    int pos = atomicAdd(u_eke + a, 1);        o_eke[pos] = b;
    int pos2 = atomicAdd(u_ekk + (b-E_N), 1); o_ekk[pos2] = a;
  }
  if(i < NSE){
    int a = ses[i], b = sed[i];
    int pos = atomicAdd(u_see + a, 1);        o_see[pos] = b;
    int pos2 = atomicAdd(u_ses + (b-E_N), 1); o_ses[pos2] = a;
  }
}

// ---- per-layer state convert: f32 -> bf16 hi/lo + P = exp(h·wa) per gate ----
__global__ __launch_bounds__(256) void k_cvt(const float* __restrict__ kn, const float* __restrict__ ex,
    const float* __restrict__ st,
    unsigned short* __restrict__ knb, unsigned short* __restrict__ exb, unsigned short* __restrict__ stb,
    const float* __restrict__ wa, int l4,
    float* __restrict__ Pefk, float* __restrict__ Pkfe, float* __restrict__ Pufe, float* __restrict__ Pefu){
  int w = (blockIdx.x*256 + threadIdx.x) >> 6;
  int lane = threadIdx.x & 63;
  const float* src; unsigned short *hi, *lo; int r;
  const float* wv1; const float* wv2 = nullptr; float *P1, *P2 = nullptr;
  if(w < K_N){ r = w; src = kn + (size_t)r*128; hi = knb; lo = knb + (size_t)K_N*128;
               wv1 = wa + (size_t)(l4+1)*128; P1 = Pefk; }
  else if(w < K_N + E_N){ r = w - K_N; src = ex + (size_t)r*128; hi = exb; lo = exb + (size_t)E_N*128;
               wv1 = wa + (size_t)(l4+0)*128; P1 = Pkfe;
               wv2 = wa + (size_t)(l4+2)*128; P2 = Pufe; }
  else { r = w - K_N - E_N; if(r >= S_N) return; src = st + (size_t)r*128; hi = stb; lo = stb + (size_t)S_N*128;
               wv1 = wa + (size_t)(l4+3)*128; P1 = Pefu; }
  float2 x = ((const float2*)src)[lane];
  float2 v1 = ((const float2*)wv1)[lane];
  float d1 = x.x*v1.x + x.y*v1.y;
  float d2 = 0.f;
  if(wv2){ float2 v2 = ((const float2*)wv2)[lane]; d2 = x.x*v2.x + x.y*v2.y; }
  #pragma unroll
  for(int off=1; off<64; off<<=1){ d1 += __shfl_xor(d1,off); d2 += __shfl_xor(d2,off); }
  if(lane==0){ P1[r] = expf(d1); if(P2) P2[r] = expf(d2); }
  unsigned short h0 = f2bf(x.x), h1 = f2bf(x.y);
  unsigned short l0 = f2bf(x.x - bf2f(h0)), l1 = f2bf(x.y - bf2f(h1));
  ((ushort2*)(hi + (size_t)r*128))[lane] = make_ushort2(h0,h1);
  ((ushort2*)(lo + (size_t)r*128))[lane] = make_ushort2(l0,l1);
}

// ---- split-bf16 MFMA GEMM; Z output packed bf16 (RNE) via lane-pair pack ----
#define GT0 4
#define GT1 317
#define GT2 942
#define GT3 1255
__global__ __launch_bounds__(256) void k_gemm(GS g0, GS g1, GS g2, GS g3){
  int b = blockIdx.x;
  GS g; int lt;
  if(b < GT0){ g = g0; lt = b; }
  else if(b < GT1){ g = g1; lt = b - GT0; }
  else if(b < GT2){ g = g2; lt = b - GT1; }
  else { g = g3; lt = b - GT2; }
  int l = threadIdx.x & 63, wv = threadIdx.x >> 6;
  int r0 = lt*32;
  bf16x8 bh[2][4], bl[2][4];
  #pragma unroll
  for(int cs=0; cs<2; cs++)
    #pragma unroll
    for(int kt=0; kt<4; kt++){
      size_t o = (((size_t)((wv*2+cs)*4 + kt))*64 + l)*8;
      bh[cs][kt] = *(const bf16x8*)(g.Wh + o);
      bl[cs][kt] = *(const bf16x8*)(g.Wl + o);
    }
  f32x4 acc[2][2];
  #pragma unroll
  for(int rs=0;rs<2;rs++)
    #pragma unroll
    for(int cs=0;cs<2;cs++) acc[rs][cs] = (f32x4){0.f,0.f,0.f,0.f};
  #pragma unroll
  for(int kt=0; kt<4; kt++){
    bf16x8 ah[2], al[2];
    #pragma unroll
    for(int rs=0; rs<2; rs++){
      size_t ao = ((size_t)(r0 + rs*16 + (l&15)))*128 + kt*32 + (l>>4)*8;
      ah[rs] = *(const bf16x8*)(g.Ah + ao);
      al[rs] = *(const bf16x8*)(g.Al + ao);
    }
    #pragma unroll
    for(int rs=0; rs<2; rs++)
      #pragma unroll
      for(int cs=0; cs<2; cs++){
        acc[rs][cs] = __builtin_amdgcn_mfma_f32_16x16x32_bf16(ah[rs], bh[cs][kt], acc[rs][cs], 0,0,0);
        acc[rs][cs] = __builtin_amdgcn_mfma_f32_16x16x32_bf16(ah[rs], bl[cs][kt], acc[rs][cs], 0,0,0);
        acc[rs][cs] = __builtin_amdgcn_mfma_f32_16x16x32_bf16(al[rs], bh[cs][kt], acc[rs][cs], 0,0,0);
      }
  }
  // C/D layout: col = lane&15, row = (lane>>4)*4 + j.
  // Lanes l and l^1 hold adjacent cols of the SAME row -> pack 2 bf16 per dword.
  #pragma unroll
  for(int rs=0; rs<2; rs++)
    #pragma unroll
    for(int cs=0; cs<2; cs++){
      int cb = (wv<<5) + (cs<<4) + (l&15);
      #pragma unroll
      for(int j=0;j<4;j++){
        float v = acc[rs][cs][j];
        float vp = __shfl_xor(v, 1);
        int rr = r0 + rs*16 + ((l>>4)<<2) + j;
        if(!(l&1) && rr < g.rows){
          unsigned int pw = (unsigned)f2bf(v) | ((unsigned)f2bf(vp)<<16);
          *(unsigned int*)(g.Z + (size_t)rr*128 + cb) = pw;
        }
      }
    }
}

// ---- quarter-per-row segment aggregation: 16 lanes OWN one row (16B/lane slice).
// unroll-4 over consecutive edges -> 4 independent gathers in flight per quarter,
// 16 per wave. No cross-quarter reduction (den identical across quarter lanes). ----
#define BFACC(zz, xx) \
  a[0] += xx*__uint_as_float(zz.x<<16); a[1] += xx*__uint_as_float(zz.x&0xffff0000u); \
  a[2] += xx*__uint_as_float(zz.y<<16); a[3] += xx*__uint_as_float(zz.y&0xffff0000u); \
  a[4] += xx*__uint_as_float(zz.z<<16); a[5] += xx*__uint_as_float(zz.z&0xffff0000u); \
  a[6] += xx*__uint_as_float(zz.w<<16); a[7] += xx*__uint_as_float(zz.w&0xffff0000u);

__device__ __forceinline__ void seg_row_q4(const unsigned short* __restrict__ z, const float* __restrict__ p,
                                           const int* __restrict__ col, int e0, int e1,
                                           int l16, float* a, float& denO){
  #pragma unroll
  for(int j=0;j<8;j++) a[j] = 0.f;
  float den = 0.f;
  const unsigned short* zl = z + l16*8;
  int e = e0;
  for(; e + 3 < e1; e += 4){
    int cA = col[e], cB = col[e+1], cC = col[e+2], cD = col[e+3];
    float xA = p[cA], xB = p[cB], xC = p[cC], xD = p[cD];
    uint4 zA = *(const uint4*)(zl + (size_t)cA*128);
    uint4 zB = *(const uint4*)(zl + (size_t)cB*128);
    uint4 zC = *(const uint4*)(zl + (size_t)cC*128);
    uint4 zD = *(const uint4*)(zl + (size_t)cD*128);
    BFACC(zA,xA) BFACC(zB,xB) BFACC(zC,xC) BFACC(zD,xD)
    den += (xA + xB) + (xC + xD);
  }
  for(; e < e1; e++){
    int cA = col[e];
    float xA = p[cA];
    uint4 zA = *(const uint4*)(zl + (size_t)cA*128);
    BFACC(zA,xA)
    den += xA;
  }
  denO = den;
}

// ---- fused segment + gate kernel. Quarter-per-row grid:
// [0,625): ex rows (16/block) — ek + se segs per quarter, gate, write ex_f.
// [625,1875): st rows (16/block) — ses + base -> st_f.
// [1875,2003): kn rows — block-per-row, 16 streams, + base -> kn_f.
#define S2A 625
#define S2B 1875
#define S2C 2003
__global__ __launch_bounds__(256) void k_seg2(
    const unsigned short* __restrict__ zB, const float* __restrict__ pB, const int* __restrict__ rpB, const int* __restrict__ colB,
    const unsigned short* __restrict__ zC, const float* __restrict__ pC, const int* __restrict__ rpC, const int* __restrict__ colC,
    const unsigned short* __restrict__ zS, const float* __restrict__ pS, const int* __restrict__ rpS, const int* __restrict__ colS,
    const float* __restrict__ stBase, float* __restrict__ stOut,
    const unsigned short* __restrict__ zK, const float* __restrict__ pK, const int* __restrict__ rpK, const int* __restrict__ colK,
    const float* __restrict__ knBase, float* __restrict__ knOut,
    const float* __restrict__ exBase, float* __restrict__ exOut,
    const float* __restrict__ Fwl, const float* __restrict__ Fbl){
  __shared__ float4 red0[4][16];
  __shared__ float4 red1[4][16];
  __shared__ float redd[4];
  int b = blockIdx.x;
  int lane = threadIdx.x & 63, wid = threadIdx.x >> 6;
  int q = lane >> 4, l16 = lane & 15;
  if(b < S2A){
    int row = b*16 + wid*4 + q;              // ex row, < 10000 (625*16)
    float B[8], C[8]; float dB, dC;
    seg_row_q4(zB, pB, colB, rpB[row], rpB[row+1], l16, B, dB);
    seg_row_q4(zC, pC, colC, rpC[row], rpC[row+1], l16, C, dC);
    float invB = dB > 0.f ? 1.f/dB : 0.f;
    float invC = dC > 0.f ? 1.f/dC : 0.f;
    #pragma unroll
    for(int j=0;j<8;j++){ B[j]*=invB; C[j]*=invC; }
    const float4* exr = (const float4*)(exBase + (size_t)row*128) + l16*2;
    float4 ea = exr[0], eb = exr[1];
    float ex8[8] = {ea.x,ea.y,ea.z,ea.w, eb.x,eb.y,eb.z,eb.w};
    float s1 = 0.f, s2 = 0.f;
    #pragma unroll
    for(int j=0;j<8;j++){
      s1 += ex8[j]*Fwl[l16*8+j]       + B[j]*Fwl[128+l16*8+j];
      s2 += ex8[j]*Fwl[256+l16*8+j]   + C[j]*Fwl[384+l16*8+j];
    }
    #pragma unroll
    for(int off=1; off<16; off<<=1){ s1 += __shfl_xor(s1,off); s2 += __shfl_xor(s2,off); }
    s1 += Fbl[0]; s2 += Fbl[1];
    float mx = fmaxf(s1,s2);
    float pp = expf(s1-mx), qq = expf(s2-mx);
    float iv = 1.f/(pp+qq);
    pp *= iv; qq *= iv;
    float4* orow = (float4*)(exOut + (size_t)row*128) + l16*2;
    orow[0] = (float4){ex8[0] + pp*B[0] + qq*C[0], ex8[1] + pp*B[1] + qq*C[1],
                       ex8[2] + pp*B[2] + qq*C[2], ex8[3] + pp*B[3] + qq*C[3]};
    orow[1] = (float4){ex8[4] + pp*B[4] + qq*C[4], ex8[5] + pp*B[5] + qq*C[5],
                       ex8[6] + pp*B[6] + qq*C[6], ex8[7] + pp*B[7] + qq*C[7]};
  } else if(b < S2B){
    int row = (b-S2A)*16 + wid*4 + q;        // st row, < 20000 (1250*16)
    float a[8]; float den;
    seg_row_q4(zS, pS, colS, rpS[row], rpS[row+1], l16, a, den);
    float inv = den > 0.f ? 1.f/den : 0.f;
    const float4* br = (const float4*)(stBase + (size_t)row*128) + l16*2;
    float4 b0 = br[0], b1 = br[1];
    float4* orow = (float4*)(stOut + (size_t)row*128) + l16*2;
    orow[0] = (float4){a[0]*inv + b0.x, a[1]*inv + b0.y, a[2]*inv + b0.z, a[3]*inv + b0.w};
    orow[1] = (float4){a[4]*inv + b1.x, a[5]*inv + b1.y, a[6]*inv + b1.z, a[7]*inv + b1.w};
  } else {
    int row = b - S2B;                       // kn row, < 128; 16 streams
    int e0 = rpK[row], e1 = rpK[row+1];
    float a[8];
    #pragma unroll
    for(int j=0;j<8;j++) a[j]=0.f;
    float den = 0.f;
    const unsigned short* zl = zK + l16*8;
    int str = wid*4 + q;
    int e = e0 + str;
    for(; e + 48 < e1; e += 64){
      int cA = colK[e], cB = colK[e+16], cC = colK[e+32], cD = colK[e+48];
      float xA = pK[cA], xB = pK[cB], xC = pK[cC], xD = pK[cD];
      uint4 zA = *(const uint4*)(zl + (size_t)cA*128);
      uint4 zB = *(const uint4*)(zl + (size_t)cB*128);
      uint4 zC = *(const uint4*)(zl + (size_t)cC*128);
      uint4 zD = *(const uint4*)(zl + (size_t)cD*128);
      BFACC(zA,xA) BFACC(zB,xB) BFACC(zC,xC) BFACC(zD,xD)
      den += (xA + xB) + (xC + xD);
    }
    for(; e < e1; e += 16){
      int cA = colK[e];
      float xA = pK[cA];
      uint4 zA = *(const uint4*)(zl + (size_t)cA*128);
      BFACC(zA,xA)
      den += xA;
    }
    #pragma unroll
    for(int j=0;j<8;j++){ a[j] += __shfl_xor(a[j],16); a[j] += __shfl_xor(a[j],32); }
    den += __shfl_xor(den,16); den += __shfl_xor(den,32);
    if(lane < 16){
      red0[wid][l16] = (float4){a[0],a[1],a[2],a[3]};
      red1[wid][l16] = (float4){a[4],a[5],a[6],a[7]};
      if(l16==0) redd[wid] = den;
    }
    __syncthreads();
    if(wid) return;
    float4 a0 = red0[0][l16], a1 = red1[0][l16]; den = redd[0];
    #pragma unroll
    for(int i=1;i<4;i++){
      float4 r0 = red0[i][l16], r1 = red1[i][l16];
      a0.x+=r0.x; a0.y+=r0.y; a0.z+=r0.z; a0.w+=r0.w;
      a1.x+=r1.x; a1.y+=r1.y; a1.z+=r1.z; a1.w+=r1.w;
      den += redd[i];
    }
    float inv = den > 0.f ? 1.f/den : 0.f;
    if(q==0){
      const float4* br = (const float4*)(knBase + (size_t)row*128) + l16*2;
      float4 b0 = br[0], b1 = br[1];
      float4* orow = (float4*)(knOut + (size_t)row*128) + l16*2;
      orow[0] = (float4){a0.x*inv + b0.x, a0.y*inv + b0.y, a0.z*inv + b0.z, a0.w*inv + b0.w};
      orow[1] = (float4){a1.x*inv + b1.x, a1.y*inv + b1.y, a1.z*inv + b1.z, a1.w*inv + b1.w};
    }
  }
}

// ---- fused outputs ----
__global__ __launch_bounds__(256) void k_out(const float* __restrict__ st, const float* __restrict__ ex,
    const float* __restrict__ kn, const float* __restrict__ disc,
    const int* __restrict__ sid, const int* __restrict__ eid,
    float* out0, float* out1, float* out2, float* out3){
  int w = (blockIdx.x*256 + threadIdx.x) >> 6;
  int lane = threadIdx.x & 63;
  const int ROWW = 3*B_N*64;
  if(w < ROWW){
    int half = lane>>5, l32 = lane&31;
    int r = w*2 + half;
    int sec = r >> 18;              // B_N*128 = 2^18
    int rr = r & 262143;
    int b = rr >> 7, i = rr & 127;
    const float* emb; int srow; float* ob;
    if(sec==0){ emb=st; srow=sid[b]; ob=out0; }
    else if(sec==1){ emb=ex; srow=eid[b]; ob=out1; }
    else { emb=kn; srow=i; ob=out3; }
    f32x4 v = *((const f32x4*)(emb + (size_t)srow*128) + l32);
    __builtin_nontemporal_store(v, (f32x4*)(ob + (size_t)rr*128) + l32);
  } else {
    int i = (w - ROWW)*64 + lane;
    if(i < B_N) out2[i] = disc[eid[i]];
  }
}

extern "C" void kernel_launch(void* const* d_in, const int* in_sizes, int n_in,
                              void* d_out, int out_size, void* d_ws, size_t ws_size,
                              hipStream_t stream){
  (void)in_sizes; (void)out_size; (void)ws_size;
  const float* stu_emb  = (const float*)d_in[0];
  const float* exer_emb = (const float*)d_in[1];
  const float* kn_emb   = (const float*)d_in[2];
  const float* disc_emb = (const float*)d_in[3];
  const float* GW = (const float*)d_in[4];
  const float* Ga = (const float*)d_in[5];
  const float* Fw = (const float*)d_in[6];
  const float* Fb = (const float*)d_in[7];
  int base = n_in - 6;
  const int* sid    = (const int*)d_in[base];
  const int* eid    = (const int*)d_in[base+1];
  const int* ek_src = (const int*)d_in[base+2];
  const int* ek_dst = (const int*)d_in[base+3];
  const int* se_src = (const int*)d_in[base+4];
  const int* se_dst = (const int*)d_in[base+5];

  char* w = (char*)d_ws;
  size_t off = 0;
  auto alloc = [&](size_t bytes)->char*{ char* p = w + off; off += (bytes + 255) & ~(size_t)255; return p; };
  float* st_f = (float*)alloc((size_t)S_N*D_N*4);
  float* ex_f = (float*)alloc((size_t)E_N*D_N*4);
  float* kn_f = (float*)alloc((size_t)K_N*D_N*4);
  unsigned short* zefk = (unsigned short*)alloc((size_t)K_N*D_N*2);
  unsigned short* zkfe = (unsigned short*)alloc((size_t)E_N*D_N*2);
  unsigned short* zefu = (unsigned short*)alloc((size_t)S_N*D_N*2);
  unsigned short* zufe = (unsigned short*)alloc((size_t)E_N*D_N*2);
  float* Pefk = (float*)alloc((size_t)K_N*4);
  float* Pkfe = (float*)alloc((size_t)E_N*4);
  float* Pefu = (float*)alloc((size_t)S_N*4);
  float* Pufe = (float*)alloc((size_t)E_N*4);
  unsigned short* knb = (unsigned short*)alloc((size_t)K_N*D_N*2*2 + 4096);
  unsigned short* exb = (unsigned short*)alloc((size_t)E_N*D_N*2*2 + 4096);
  unsigned short* stb = (unsigned short*)alloc((size_t)S_N*D_N*2*2 + 4096);
  unsigned short* wf  = (unsigned short*)alloc((size_t)16*16384*2);
  float* wa   = (float*)alloc((size_t)8*128*4);
  int*   cnt  = (int*)alloc((size_t)(2*E_N+K_N+S_N)*4);
  int*   rp   = (int*)alloc((size_t)(2*(E_N+1)+(K_N+1)+(S_N+1))*4);
  int*   cur  = (int*)alloc((size_t)(2*E_N+K_N+S_N)*4);
  int*   col  = (int*)alloc((size_t)(2*NEK+2*NSE)*4);

  int* cnt_eke = cnt;                 int* cnt_ekk = cnt + E_N;
  int* cnt_see = cnt + E_N + K_N;     int* cnt_ses = cnt + 2*E_N + K_N;
  int* cur_eke = cur;                 int* cur_ekk = cur + E_N;
  int* cur_see = cur + E_N + K_N;     int* cur_ses = cur + 2*E_N + K_N;
  int* rp_eke = rp;                                int* rp_ekk = rp + (E_N+1);
  int* rp_see = rp + (E_N+1) + (K_N+1);            int* rp_ses = rp + 2*(E_N+1) + (K_N+1);
  int* col_eke = col;                 int* col_ekk = col + NEK;
  int* col_see = col + 2*NEK;         int* col_ses = col + 2*NEK + NSE;

  // ---- setup: hist(+wprep) -> scan -> fill ----
  hipMemsetAsync(cnt, 0, (size_t)(2*E_N+K_N+S_N)*4, stream);
  k_hist<<<HB+8,256,0,stream>>>(ek_src, ek_dst, se_src, se_dst,
                                cnt_eke, cnt_ekk, cnt_see, cnt_ses,
                                GW, Ga, wf, wa);
  k_scan<<<4,1024,0,stream>>>(CSet{cnt_eke,E_N,rp_eke,cur_eke}, CSet{cnt_ekk,K_N,rp_ekk,cur_ekk},
                              CSet{cnt_see,E_N,rp_see,cur_see}, CSet{cnt_ses,S_N,rp_ses,cur_ses});
  k_fill<<<HB,256,0,stream>>>(ek_src, ek_dst, se_src, se_dst,
                              cur_eke, cur_ekk, cur_see, cur_ses,
                              col_eke, col_ekk, col_see, col_ses);

  const unsigned short* knb_lo = knb + (size_t)K_N*128;
  const unsigned short* exb_lo = exb + (size_t)E_N*128;
  const unsigned short* stb_lo = stb + (size_t)S_N*128;

  for(int l=0; l<2; l++){
    const float* knp = l ? kn_f : kn_emb;
    const float* exp_ = l ? ex_f : exer_emb;
    const float* stp = l ? st_f : stu_emb;
    int l4 = l*4;
    // state -> bf16 hi/lo + pre-exp'd attention scores (once per element)
    k_cvt<<<(K_N+E_N+S_N)/4,256,0,stream>>>(knp, exp_, stp, knb, exb, stb, wa, l4,
                                            Pefk, Pkfe, Pufe, Pefu);
    // 4 gemms, one dispatch: gates (l4+1: kn), (l4+0: ex), (l4+3: st), (l4+2: ex)
    GS g0{knb, knb_lo, wf + (size_t)(l4+1)*16384, wf + (size_t)(8+l4+1)*16384, zefk, K_N};
    GS g1{exb, exb_lo, wf + (size_t)(l4+0)*16384, wf + (size_t)(8+l4+0)*16384, zkfe, E_N};
    GS g2{stb, stb_lo, wf + (size_t)(l4+3)*16384, wf + (size_t)(8+l4+3)*16384, zefu, S_N};
    GS g3{exb, exb_lo, wf + (size_t)(l4+2)*16384, wf + (size_t)(8+l4+2)*16384, zufe, E_N};
    k_gemm<<<GT3,256,0,stream>>>(g0,g1,g2,g3);
    // fused aggregations + ex gate, one dispatch (quarter-per-row)
    k_seg2<<<S2C,256,0,stream>>>(
      zefk - (size_t)E_N*128, Pefk - E_N, rp_eke, col_eke,     // efk (ek by ex)
      zefu - (size_t)E_N*128, Pefu - E_N, rp_see, col_see,     // efu (se by ex)
      zufe, Pufe, rp_ses, col_ses, stp, st_f,                  // ufe -> st_f
      zkfe, Pkfe, rp_ekk, col_ekk, knp, kn_f,                  // kfe -> kn_f
      exp_, ex_f, Fw + (size_t)l*3*2*D_N, Fb + (size_t)l*3);   // gate
  }

  float* out  = (float*)d_out;
  float* out0 = out;                           // stu_ts  (B,D,D)
  float* out1 = out0 + (size_t)B_N*D_N*D_N;    // exer_ts (B,D,D)
  float* out2 = out1 + (size_t)B_N*D_N*D_N;    // disc    (B,1)
  float* out3 = out2 + (size_t)B_N;            // kn_ts   (B,K,D)
  int waves = 3*B_N*64 + 32;
  k_out<<<(waves+3)/4,256,0,stream>>>(st_f, ex_f, kn_f, disc_emb, sid, eid, out0, out1, out2, out3);
}